// Round 2
// baseline (267.222 us; speedup 1.0000x reference)
//
#include <hip/hip_runtime.h>
#include <hip/hip_bf16.h>
#include <math.h>

#define L_SEQ 8192
#define B_BATCH 8
#define D_DIM 256
#define BL (B_BATCH * L_SEQ)
#define EPS_F 1.1920929e-07f

typedef __attribute__((ext_vector_type(8))) short short8;
typedef __attribute__((ext_vector_type(4))) float f32x4;
typedef __attribute__((ext_vector_type(4))) unsigned short u16x4;

// ws layout (bytes):
//   [0,       262144)  M fp32 256x256  (dead after k_packB)  ∪ starts int32 BL (k_scan+)
//   [262144,  524288)  Bpack bf16: 2 segs (M1,M2) x 8 k8 x 16 ct fragments x 64 lanes x 8
//   [524288,  589824)  hard  uint8  BL
//   [589824,  589856)  n_b   int32  8
//   [589856,  589888)  len   int32  8

__device__ inline unsigned short f2bf(float x) {
    __hip_bfloat16 b = __float2bfloat16(x);
    return *(unsigned short*)&b;
}
__device__ inline float bf2f(unsigned short u) {
    __hip_bfloat16 b = *(__hip_bfloat16*)&u;
    return __bfloat162float(b);
}

// ---------------------------------------------------------------- K1: M = Wq^T * Wk
__global__ void k_matM(const float* __restrict__ Wq, const float* __restrict__ Wk,
                       float* __restrict__ M) {
    __shared__ float Aq[16][17];
    __shared__ float Ak[16][17];
    const int tx = threadIdx.x, ty = threadIdx.y;
    const int d  = blockIdx.y * 16 + ty;   // row of M
    const int dp = blockIdx.x * 16 + tx;   // col of M
    float acc = 0.f;
    for (int e0 = 0; e0 < 256; e0 += 16) {
        Aq[ty][tx] = Wq[(e0 + ty) * 256 + blockIdx.y * 16 + tx];
        Ak[ty][tx] = Wk[(e0 + ty) * 256 + blockIdx.x * 16 + tx];
        __syncthreads();
#pragma unroll
        for (int i = 0; i < 16; ++i) acc += Aq[i][ty] * Ak[i][tx];
        __syncthreads();
    }
    M[d * 256 + dp] = acc;
}

// ------------------------- K2: pack (M - I) into bf16 hi/lo MFMA B-fragment layout
// B-frag (16x16x32 bf16): lane holds B[k = k8*32 + (lane>>4)*8 + j][n = ct*16 + (lane&15)]
// Bpack[seg][k8][ct] fragment = 64 lanes x 8 bf16 (1 KB), lane-linear (coalesced b128).
__global__ void k_packB(const float* __restrict__ M, unsigned short* __restrict__ Bpack) {
    const int f    = blockIdx.x;          // 0..255
    const int seg  = f >> 7;              // 0: hi(M1), 1: lo(M2)
    const int k8   = (f >> 4) & 7;
    const int ct   = f & 15;
    const int lane = threadIdx.x;         // 0..63
    const int q    = lane >> 4;
    const int n    = ct * 16 + (lane & 15);
    unsigned short v[8];
#pragma unroll
    for (int j = 0; j < 8; ++j) {
        const int k = k8 * 32 + q * 8 + j;
        const float Mm = M[k * 256 + n] - (k == n ? 1.0f : 0.0f);
        const unsigned short h = f2bf(Mm);
        v[j] = seg ? f2bf(Mm - bf2f(h)) : h;
    }
    unsigned short* dst = Bpack + (size_t)f * 512 + lane * 8;
#pragma unroll
    for (int j = 0; j < 8; ++j) dst[j] = v[j];
}

// ------------------------------ K3: normalize + MFMA correction GEMM + cos + hard bit
// Block = 256 thr = 4 waves, 64 output tokens [T0, T0+64).
// cos(t) = hn_{t-1}.hn_t (exact fp32, computed at STAGE time)
//        + hn_{t-1}^T (M-I) hn_t (bf16 hi/lo 3-term MFMA; hn_t reconstructed hi+lo).
// Stage: each wave owns a contiguous 17-row slab (rows w*16..w*16+16), normalizes,
// converts once to bf16 hi/lo into LDS, and computes the exact fp32 neighbor dots
// with the previous row kept in registers. Every LDS region (hi/lo slab rows the
// wave later reads, dots, Vscr) is written by the SAME wave -> ZERO barriers.
// Main loop: pure {ds_read_b128 A-frag + global b128 B-frags (double-buffered) + MFMA}.
#define RS 264   // LDS row stride in bf16 elems: 528 B -> uniform granule spread, b128-clean
__global__ __launch_bounds__(256, 2) void k_cosmfma(
    const float* __restrict__ hidden, const unsigned short* __restrict__ Bpack,
    const float* __restrict__ noise, unsigned char* __restrict__ hard) {
    __shared__ __attribute__((aligned(16))) unsigned short hiA[65 * RS]; // 34,320 B
    __shared__ __attribute__((aligned(16))) unsigned short loA[65 * RS]; // 34,320 B
    __shared__ __attribute__((aligned(16))) float Vscr[4][2][256];       //  8,192 B
    __shared__ float dots[64];                                           //    256 B

    const int tid  = threadIdx.x;
    const int lane = tid & 63;
    const int w    = tid >> 6;        // wave 0..3
    const int w16  = w * 16;
    const int T0   = blockIdx.x * 64;

    const short8* __restrict__ B8 = (const short8*)Bpack;

    // early-issue strip 0's B fragments; they fly during staging
    short8 bufA[16], bufB[16];
    {
        const short8* bp = B8 + lane;
#pragma unroll
        for (int ct = 0; ct < 16; ++ct) bufA[ct] = bp[ct * 64];
    }

    // ---- stage slab: rows w16..w16+16 (token T0-1+row), hi/lo bf16 + exact pair dots ----
    {
        int tok0 = T0 - 1 + w16; if (tok0 < 0) tok0 = 0;
        float4 vcur = ((const float4*)hidden)[(size_t)tok0 * 64 + lane];
        float4 hp4 = {0.f, 0.f, 0.f, 0.f};
#pragma unroll 1
        for (int ii = 0; ii <= 16; ++ii) {
            float4 vnext = vcur;
            if (ii < 16)   // next row's token = T0 + w16 + ii  (always >= 0)
                vnext = ((const float4*)hidden)[(size_t)(T0 + w16 + ii) * 64 + lane];
            float ss = vcur.x * vcur.x + vcur.y * vcur.y + vcur.z * vcur.z + vcur.w * vcur.w;
#pragma unroll
            for (int sh = 32; sh >= 1; sh >>= 1) ss += __shfl_xor(ss, sh);
            const float inv = 1.0f / fmaxf(sqrtf(ss), 1e-12f);
            float4 h4;
            h4.x = vcur.x * inv; h4.y = vcur.y * inv;
            h4.z = vcur.z * inv; h4.w = vcur.w * inv;
            const unsigned short hx = f2bf(h4.x), hy = f2bf(h4.y),
                                 hz = f2bf(h4.z), hw2 = f2bf(h4.w);
            const u16x4 hv4 = {hx, hy, hz, hw2};
            const u16x4 lv4 = {f2bf(h4.x - bf2f(hx)), f2bf(h4.y - bf2f(hy)),
                               f2bf(h4.z - bf2f(hz)), f2bf(h4.w - bf2f(hw2))};
            const int i = w16 + ii;
            *(u16x4*)&hiA[i * RS + lane * 4] = hv4;
            *(u16x4*)&loA[i * RS + lane * 4] = lv4;
            if (ii > 0) {   // exact fp32 main dot hn_{i-1}.hn_i  -> token T0 + (i-1)
                float pd = h4.x * hp4.x + h4.y * hp4.y + h4.z * hp4.z + h4.w * hp4.w;
#pragma unroll
                for (int sh = 32; sh >= 1; sh >>= 1) pd += __shfl_xor(pd, sh);
                if (lane == 0) dots[i - 1] = pd;
            }
            hp4 = h4;
            vcur = vnext;
        }
    }
    // NO __syncthreads: all LDS this wave reads below was written by this wave.

    // lane holds A[m = lane&15][k = k8*32 + (lane>>4)*8 + j]; A row m <-> LDS row w16+m
    const int m = lane & 15, q = lane >> 4;
    const unsigned short* __restrict__ hrow = &hiA[(w16 + m) * RS + q * 8];
    const unsigned short* __restrict__ lrow = &loA[(w16 + m) * RS + q * 8];

    f32x4 acc[16];
#pragma unroll
    for (int ct = 0; ct < 16; ++ct) { f32x4 z = {0.f, 0.f, 0.f, 0.f}; acc[ct] = z; }

    // 16 virtual strips: s<8 -> seg0 (h & l A-frags), s>=8 -> seg1 (h only).
    // Fragment f = s*16 + ct, lane-linear. B double-buffered (bufA/bufB).
#pragma unroll 1
    for (int sp = 0; sp < 8; ++sp) {
        const int s0 = 2 * sp, s1 = 2 * sp + 1;
        {   // prefetch s1 -> bufB
            const short8* bn = B8 + s1 * 16 * 64 + lane;
#pragma unroll
            for (int ct = 0; ct < 16; ++ct) bufB[ct] = bn[ct * 64];
        }
        {   // compute s0 with bufA
            const short8 hv = *(const short8*)(hrow + (s0 & 7) * 32);
            if (s0 < 8) {
                const short8 lv = *(const short8*)(lrow + (s0 & 7) * 32);
#pragma unroll
                for (int ct = 0; ct < 16; ++ct)
                    acc[ct] = __builtin_amdgcn_mfma_f32_16x16x32_bf16(hv, bufA[ct], acc[ct], 0, 0, 0);
#pragma unroll
                for (int ct = 0; ct < 16; ++ct)
                    acc[ct] = __builtin_amdgcn_mfma_f32_16x16x32_bf16(lv, bufA[ct], acc[ct], 0, 0, 0);
            } else {
#pragma unroll
                for (int ct = 0; ct < 16; ++ct)
                    acc[ct] = __builtin_amdgcn_mfma_f32_16x16x32_bf16(hv, bufA[ct], acc[ct], 0, 0, 0);
            }
        }
        if (sp < 7) {   // prefetch s0+2 -> bufA
            const short8* bn = B8 + (s0 + 2) * 16 * 64 + lane;
#pragma unroll
            for (int ct = 0; ct < 16; ++ct) bufA[ct] = bn[ct * 64];
        }
        {   // compute s1 with bufB
            const short8 hv = *(const short8*)(hrow + (s1 & 7) * 32);
            if (s1 < 8) {
                const short8 lv = *(const short8*)(lrow + (s1 & 7) * 32);
#pragma unroll
                for (int ct = 0; ct < 16; ++ct)
                    acc[ct] = __builtin_amdgcn_mfma_f32_16x16x32_bf16(hv, bufB[ct], acc[ct], 0, 0, 0);
#pragma unroll
                for (int ct = 0; ct < 16; ++ct)
                    acc[ct] = __builtin_amdgcn_mfma_f32_16x16x32_bf16(lv, bufB[ct], acc[ct], 0, 0, 0);
            } else {
#pragma unroll
                for (int ct = 0; ct < 16; ++ct)
                    acc[ct] = __builtin_amdgcn_mfma_f32_16x16x32_bf16(hv, bufB[ct], acc[ct], 0, 0, 0);
            }
        }
    }

    // ---- epilogue: per-wave, barrier-free. V transposed 2 rows at a time via Vscr[w]. ----
    // C/D layout: lane q=lane>>4 holds rows q*4+r (r=0..3), col = ct*16 + (lane&15).
#pragma unroll
    for (int c = 0; c < 8; ++c) {
        const int q0 = c >> 1;
        const int r0 = (2 * c) & 3;
        if (q == q0) {
#pragma unroll
            for (int ct = 0; ct < 16; ++ct) {
                Vscr[w][0][ct * 16 + m] = acc[ct][r0];
                Vscr[w][1][ct * 16 + m] = acc[ct][r0 + 1];
            }
        }
        // intra-wave LDS RAW: compiler-inserted lgkmcnt wait suffices (no barrier).
#pragma unroll
        for (int rr = 0; rr < 2; ++rr) {
            const int rl = w16 + 2 * c + rr;   // token t = T0 + rl
            const float4 vv = *(const float4*)&Vscr[w][rr][lane * 4];
            const u16x4 hu = *(const u16x4*)&hiA[(rl + 1) * RS + lane * 4];
            const u16x4 lu = *(const u16x4*)&loA[(rl + 1) * RS + lane * 4];
            float part = vv.x * (bf2f(hu.x) + bf2f(lu.x))
                       + vv.y * (bf2f(hu.y) + bf2f(lu.y))
                       + vv.z * (bf2f(hu.z) + bf2f(lu.z))
                       + vv.w * (bf2f(hu.w) + bf2f(lu.w));
#pragma unroll
            for (int sh = 32; sh >= 1; sh >>= 1) part += __shfl_xor(part, sh);
            if (lane == 0) {
                const int t = T0 + rl;
                const int l = t & (L_SEQ - 1);
                float p;
                if (l == 0) {
                    p = 1.0f;
                } else {
                    p = (1.0f - (part + dots[rl])) * 0.5f;
                    p = fminf(fmaxf(p, 0.0f), 1.0f);
                }
                p = fminf(fmaxf(p, EPS_F), 1.0f - EPS_F);
                float u = noise[t];
                u = fminf(fmaxf(u, EPS_F), 1.0f - EPS_F);
                const float z = ((logf(p) - log1pf(-p)) + logf(u)) - log1pf(-u);
                hard[t] = (z > 0.0f) ? (unsigned char)1 : (unsigned char)0;
            }
        }
    }
}

// ---------------------- K4: per-row length, forced boundary, scan -> starts, n_b, mask
__global__ void k_scan(const float* __restrict__ mask, const unsigned char* __restrict__ hard,
                       int* __restrict__ starts, int* __restrict__ nb_arr,
                       int* __restrict__ len_arr, float* __restrict__ out_short) {
    __shared__ int sc[256];
    __shared__ int s_len;
    const int b = blockIdx.x, tid = threadIdx.x;
    const int base = b * L_SEQ;

    // row length = sum(mask) (contiguous prefix of ones)
    int cnt = 0;
    const float4* m4 = (const float4*)(mask + base);
    for (int i = tid; i < L_SEQ / 4; i += 256) {
        const float4 v = m4[i];
        cnt += (v.x != 0.0f) + (v.y != 0.0f) + (v.z != 0.0f) + (v.w != 0.0f);
    }
    sc[tid] = cnt;
    __syncthreads();
    for (int ofs = 128; ofs > 0; ofs >>= 1) {
        if (tid < ofs) sc[tid] += sc[tid + ofs];
        __syncthreads();
    }
    if (tid == 0) s_len = sc[0];
    __syncthreads();
    const int len = s_len;

    // adjusted hard bits for this thread's contiguous chunk [32*tid, 32*tid+32)
    const int i0 = tid * 32;
    unsigned int bits = 0;
    int c = 0;
#pragma unroll
    for (int j = 0; j < 32; ++j) {
        const int i = i0 + j;
        int h = (i < len) ? (int)hard[base + i] : 0;
        if (len < L_SEQ && i == len - 1) h = 1;  // forced boundary at last real token
        bits |= (unsigned int)h << j;
        c += h;
    }
    __syncthreads();
    sc[tid] = c;
    __syncthreads();
    // inclusive Hillis-Steele scan over 256 thread counts
    for (int ofs = 1; ofs < 256; ofs <<= 1) {
        const int v = (tid >= ofs) ? sc[tid - ofs] : 0;
        __syncthreads();
        sc[tid] += v;
        __syncthreads();
    }
    const int off = sc[tid] - c;
    const int nb = sc[255];

    int run = off;
#pragma unroll
    for (int j = 0; j < 32; ++j)
        if ((bits >> j) & 1u) { starts[base + run] = i0 + j; ++run; }

    if (tid == 0) { nb_arr[b] = nb; len_arr[b] = len; }

    for (int i = tid; i < L_SEQ; i += 256) out_short[base + i] = (i < nb) ? 1.0f : 0.0f;
}

// --------------------------------------------- K5: one wave per segment, mean-pool
__global__ __launch_bounds__(256) void k_pool(
    const float* __restrict__ hidden, const int* __restrict__ starts,
    const int* __restrict__ nb_arr, const int* __restrict__ len_arr,
    float* __restrict__ pooled) {
    const int tid  = threadIdx.x;
    const int lane = tid & 63;
    const int wid  = blockIdx.x * 4 + (tid >> 6);
    const int b    = wid >> 13;       // / 8192
    const int s    = wid & (L_SEQ - 1);
    const int nb   = nb_arr[b];

    float4 res = {0.f, 0.f, 0.f, 0.f};
    if (s < nb) {
        const int start = (s == 0) ? 0 : starts[b * L_SEQ + s];
        const int end   = (s + 1 < nb) ? starts[b * L_SEQ + s + 1] : len_arr[b];
        float4 acc = {0.f, 0.f, 0.f, 0.f};
        for (int t = start; t < end; ++t) {
            const float4 v = ((const float4*)hidden)[(b * L_SEQ + t) * 64 + lane];
            acc.x += v.x; acc.y += v.y; acc.z += v.z; acc.w += v.w;
        }
        const float cntf = (float)(end - start);
        res.x = acc.x / cntf; res.y = acc.y / cntf; res.z = acc.z / cntf; res.w = acc.w / cntf;
    }
    ((float4*)pooled)[(size_t)wid * 64 + lane] = res;
}

// ---------------------------------------------------- K6: scalars (loss via lgamma)
__global__ void k_final(const int* __restrict__ nb_arr, const int* __restrict__ len_arr,
                        float* __restrict__ out_scal) {
    if (threadIdx.x == 0) {
        int nb = 0, ln = 0;
        for (int b = 0; b < B_BATCH; ++b) { nb += nb_arr[b]; ln += len_arr[b]; }
        const double k = (double)nb, n = (double)ln;
        const double logp = lgamma(n + 1.0) - lgamma(k + 1.0) - lgamma(n - k + 1.0)
                            + k * log(0.2) + (n - k) * log(0.8);
        const double loss = -logp / n;
        out_scal[0] = (float)loss;
        out_scal[1] = (float)nb;
        out_scal[2] = (float)ln;
    }
}

extern "C" void kernel_launch(void* const* d_in, const int* in_sizes, int n_in,
                              void* d_out, int out_size, void* d_ws, size_t ws_size,
                              hipStream_t stream) {
    const float* hidden = (const float*)d_in[0];
    const float* Wq     = (const float*)d_in[1];
    const float* Wk     = (const float*)d_in[2];
    const float* noise  = (const float*)d_in[3];
    const float* mask   = (const float*)d_in[4];
    float* out = (float*)d_out;
    char* ws = (char*)d_ws;

    float*          M      = (float*)(ws);                 // dead after k_packB
    int*            starts = (int*)(ws);                   // reuses M region (k_scan onward)
    unsigned short* Bpack  = (unsigned short*)(ws + 262144);
    unsigned char*  hard   = (unsigned char*)(ws + 524288);
    int*            nb_arr = (int*)(ws + 589824);
    int*            len_arr= (int*)(ws + 589856);

    float* pooled = out;
    float* scal   = out + (size_t)BL * D_DIM;
    float* shortm = scal + 3;

    k_matM   <<<dim3(16, 16), dim3(16, 16), 0, stream>>>(Wq, Wk, M);
    k_packB  <<<256, 64, 0, stream>>>(M, Bpack);
    k_cosmfma<<<BL / 64, 256, 0, stream>>>(hidden, Bpack, noise, hard);
    k_scan   <<<B_BATCH, 256, 0, stream>>>(mask, hard, starts, nb_arr, len_arr, shortm);
    k_pool   <<<BL / 4, 256, 0, stream>>>(hidden, starts, nb_arr, len_arr, pooled);
    k_final  <<<1, 64, 0, stream>>>(nb_arr, len_arr, scal);
}

// Round 3
// 208.146 us; speedup vs baseline: 1.2838x; 1.2838x over previous
//
#include <hip/hip_runtime.h>
#include <hip/hip_bf16.h>
#include <math.h>

#define L_SEQ 8192
#define B_BATCH 8
#define D_DIM 256
#define BL (B_BATCH * L_SEQ)
#define EPS_F 1.1920929e-07f

typedef __attribute__((ext_vector_type(8))) short short8;
typedef __attribute__((ext_vector_type(4))) float f32x4;
typedef __attribute__((ext_vector_type(4))) unsigned short u16x4;

// ws layout (bytes):
//   [0,       262144)  M fp32 256x256  (dead after k_packB)  ∪ starts int32 BL (k_scan+)
//   [262144,  524288)  Bpack bf16: 2 segs (M1,M2) x 8 k8 x 16 ct fragments x 64 lanes x 8
//   [524288,  589824)  hard  uint8  BL
//   [589824,  589856)  n_b   int32  8
//   [589856,  589888)  len   int32  8

__device__ inline unsigned short f2bf(float x) {
    __hip_bfloat16 b = __float2bfloat16(x);
    return *(unsigned short*)&b;
}
__device__ inline float bf2f(unsigned short u) {
    __hip_bfloat16 b = *(__hip_bfloat16*)&u;
    return __bfloat162float(b);
}

// ---------------------------------------------------------------- K1: M = Wq^T * Wk
__global__ void k_matM(const float* __restrict__ Wq, const float* __restrict__ Wk,
                       float* __restrict__ M) {
    __shared__ float Aq[16][17];
    __shared__ float Ak[16][17];
    const int tx = threadIdx.x, ty = threadIdx.y;
    const int d  = blockIdx.y * 16 + ty;   // row of M
    const int dp = blockIdx.x * 16 + tx;   // col of M
    float acc = 0.f;
    for (int e0 = 0; e0 < 256; e0 += 16) {
        Aq[ty][tx] = Wq[(e0 + ty) * 256 + blockIdx.y * 16 + tx];
        Ak[ty][tx] = Wk[(e0 + ty) * 256 + blockIdx.x * 16 + tx];
        __syncthreads();
#pragma unroll
        for (int i = 0; i < 16; ++i) acc += Aq[i][ty] * Ak[i][tx];
        __syncthreads();
    }
    M[d * 256 + dp] = acc;
}

// ------------------------- K2: pack (M - I) into bf16 hi/lo MFMA B-fragment layout
// B-frag (16x16x32 bf16): lane holds B[k = k8*32 + (lane>>4)*8 + j][n = ct*16 + (lane&15)]
// Bpack[seg][k8][ct] fragment = 64 lanes x 8 bf16 (1 KB), lane-linear (coalesced b128).
__global__ void k_packB(const float* __restrict__ M, unsigned short* __restrict__ Bpack) {
    const int f    = blockIdx.x;          // 0..255
    const int seg  = f >> 7;              // 0: hi(M1), 1: lo(M2)
    const int k8   = (f >> 4) & 7;
    const int ct   = f & 15;
    const int lane = threadIdx.x;         // 0..63
    const int q    = lane >> 4;
    const int n    = ct * 16 + (lane & 15);
    unsigned short v[8];
#pragma unroll
    for (int j = 0; j < 8; ++j) {
        const int k = k8 * 32 + q * 8 + j;
        const float Mm = M[k * 256 + n] - (k == n ? 1.0f : 0.0f);
        const unsigned short h = f2bf(Mm);
        v[j] = seg ? f2bf(Mm - bf2f(h)) : h;
    }
    unsigned short* dst = Bpack + (size_t)f * 512 + lane * 8;
#pragma unroll
    for (int j = 0; j < 8; ++j) dst[j] = v[j];
}

// ------------------------------ K3: normalize + MFMA correction GEMM + cos + hard bit
// Block = 256 thr = 4 waves, 64 output tokens [T0, T0+64).
// cos(t) = hn_{t-1}.hn_t (exact fp32, computed at STAGE time)
//        + hn_{t-1}^T (M-I) hn_t (bf16 hi/lo 3-term MFMA; hn_t reconstructed hi+lo).
// v3 changes vs v2 (which spilled: VGPR_Count 128, WRITE_SIZE 21 MB of scratch):
//  - B pipeline at HALF-strip granularity: bufE/bufO of 8 frags each (64 VGPR total,
//    not 128) with one-group lookahead. acc 64 + buf 64 + hv/lv 8 + addr ~ 170 VGPR.
//  - Epilogue without Vscr/LDS transpose: each 16-lane group q owns output rows
//    q*4+r directly from the C/D layout; 4-step shfl_xor reduce within the group.
//    4x more parallel, -8 KB LDS, no barriers.
//  - Staging prefetch 2 rows deep.
#define RS 264   // LDS row stride in bf16 elems: 528 B
__global__ __launch_bounds__(256, 2) void k_cosmfma(
    const float* __restrict__ hidden, const unsigned short* __restrict__ Bpack,
    const float* __restrict__ noise, unsigned char* __restrict__ hard) {
    __shared__ __attribute__((aligned(16))) unsigned short hiA[65 * RS]; // 34,320 B
    __shared__ __attribute__((aligned(16))) unsigned short loA[65 * RS]; // 34,320 B
    __shared__ float dots[64];                                           //    256 B

    const int tid  = threadIdx.x;
    const int lane = tid & 63;
    const int w    = tid >> 6;        // wave 0..3
    const int w16  = w * 16;
    const int T0   = blockIdx.x * 64;

    const short8* __restrict__ B8 = (const short8*)Bpack;

    // early-issue strip 0's first half; flies during staging
    short8 bufE[8], bufO[8];
    {
        const short8* bp = B8 + lane;
#pragma unroll
        for (int c2 = 0; c2 < 8; ++c2) bufE[c2] = bp[c2 * 64];
    }

    // ---- stage slab: rows w16..w16+16 (token T0-1+row), hi/lo bf16 + exact pair dots ----
    {
        int tokA = T0 - 1 + w16; if (tokA < 0) tokA = 0;       // row w16
        float4 vb0 = ((const float4*)hidden)[(size_t)tokA * 64 + lane];
        float4 vb1 = ((const float4*)hidden)[(size_t)(T0 + w16) * 64 + lane];  // row w16+1
        float4 hp4 = {0.f, 0.f, 0.f, 0.f};
#pragma unroll 1
        for (int ii = 0; ii <= 16; ++ii) {
            const float4 vcur = vb0;
            vb0 = vb1;
            if (ii + 2 <= 16)   // prefetch row w16+ii+2 = token T0+w16+ii+1
                vb1 = ((const float4*)hidden)[(size_t)(T0 + w16 + ii + 1) * 64 + lane];
            float ss = vcur.x * vcur.x + vcur.y * vcur.y + vcur.z * vcur.z + vcur.w * vcur.w;
#pragma unroll
            for (int sh = 32; sh >= 1; sh >>= 1) ss += __shfl_xor(ss, sh);
            const float inv = 1.0f / fmaxf(sqrtf(ss), 1e-12f);
            float4 h4;
            h4.x = vcur.x * inv; h4.y = vcur.y * inv;
            h4.z = vcur.z * inv; h4.w = vcur.w * inv;
            const unsigned short hx = f2bf(h4.x), hy = f2bf(h4.y),
                                 hz = f2bf(h4.z), hw2 = f2bf(h4.w);
            const u16x4 hv4 = {hx, hy, hz, hw2};
            const u16x4 lv4 = {f2bf(h4.x - bf2f(hx)), f2bf(h4.y - bf2f(hy)),
                               f2bf(h4.z - bf2f(hz)), f2bf(h4.w - bf2f(hw2))};
            const int i = w16 + ii;
            *(u16x4*)&hiA[i * RS + lane * 4] = hv4;
            *(u16x4*)&loA[i * RS + lane * 4] = lv4;
            if (ii > 0) {   // exact fp32 main dot hn_{i-1}.hn_i  -> token T0 + (i-1)
                float pd = h4.x * hp4.x + h4.y * hp4.y + h4.z * hp4.z + h4.w * hp4.w;
#pragma unroll
                for (int sh = 32; sh >= 1; sh >>= 1) pd += __shfl_xor(pd, sh);
                if (lane == 0) dots[i - 1] = pd;
            }
            hp4 = h4;
        }
    }
    // NO __syncthreads: all LDS this wave reads below was written by this wave.

    // lane holds A[m = lane&15][k = k8*32 + (lane>>4)*8 + j]; A row m <-> LDS row w16+m
    const int m = lane & 15, q = lane >> 4;
    const unsigned short* __restrict__ hrow = &hiA[(w16 + m) * RS + q * 8];
    const unsigned short* __restrict__ lrow = &loA[(w16 + m) * RS + q * 8];

    f32x4 acc[16];
#pragma unroll
    for (int ct = 0; ct < 16; ++ct) { f32x4 z = {0.f, 0.f, 0.f, 0.f}; acc[ct] = z; }

    // 16 virtual strips: s<8 -> seg0 (h & l A-frags), s>=8 -> seg1 (h only).
    // Half-strip pipeline: bufE holds frags[s][0..8) on entry; load bufO=[8..16),
    // MFMA bufE, load next strip's bufE, MFMA bufO. 64 VGPR of B buffer total.
#pragma unroll 1
    for (int s = 0; s < 16; ++s) {
        const short8* bp = B8 + s * 16 * 64 + lane;
        {   // load second half of this strip
#pragma unroll
            for (int c2 = 0; c2 < 8; ++c2) bufO[c2] = bp[(8 + c2) * 64];
        }
        const short8 hv = *(const short8*)(hrow + (s & 7) * 32);
        short8 lv;
        if (s < 8) lv = *(const short8*)(lrow + (s & 7) * 32);
#pragma unroll
        for (int c2 = 0; c2 < 8; ++c2)
            acc[c2] = __builtin_amdgcn_mfma_f32_16x16x32_bf16(hv, bufE[c2], acc[c2], 0, 0, 0);
        if (s < 8) {
#pragma unroll
            for (int c2 = 0; c2 < 8; ++c2)
                acc[c2] = __builtin_amdgcn_mfma_f32_16x16x32_bf16(lv, bufE[c2], acc[c2], 0, 0, 0);
        }
        if (s < 15) {   // prefetch first half of next strip
            const short8* bn = B8 + (s + 1) * 16 * 64 + lane;
#pragma unroll
            for (int c2 = 0; c2 < 8; ++c2) bufE[c2] = bn[c2 * 64];
        }
#pragma unroll
        for (int c2 = 0; c2 < 8; ++c2)
            acc[8 + c2] = __builtin_amdgcn_mfma_f32_16x16x32_bf16(hv, bufO[c2], acc[8 + c2], 0, 0, 0);
        if (s < 8) {
#pragma unroll
            for (int c2 = 0; c2 < 8; ++c2)
                acc[8 + c2] = __builtin_amdgcn_mfma_f32_16x16x32_bf16(lv, bufO[c2], acc[8 + c2], 0, 0, 0);
        }
    }

    // ---- epilogue: direct from C/D layout, no LDS transpose, no barriers. ----
    // Lane group q (lanes q*16..q*16+15) holds rows q*4+r (r=0..3) in acc[ct][r],
    // col d = ct*16 + m. Dot V[row] . hn[row+1] : lane sums its 16 ct columns,
    // then shfl_xor 1/2/4/8 reduces across the 16-lane group.
#pragma unroll
    for (int r = 0; r < 4; ++r) {
        const int rl = w16 + q * 4 + r;   // slab row; token t = T0 + rl
        float part = 0.f;
#pragma unroll
        for (int ct = 0; ct < 16; ++ct) {
            const int idx = (rl + 1) * RS + ct * 16 + m;
            const float hd = bf2f(hiA[idx]) + bf2f(loA[idx]);
            part += acc[ct][r] * hd;
        }
        part += __shfl_xor(part, 1);
        part += __shfl_xor(part, 2);
        part += __shfl_xor(part, 4);
        part += __shfl_xor(part, 8);
        if (m == 0) {
            const int t = T0 + rl;
            const int l = t & (L_SEQ - 1);
            float p;
            if (l == 0) {
                p = 1.0f;
            } else {
                p = (1.0f - (part + dots[rl])) * 0.5f;
                p = fminf(fmaxf(p, 0.0f), 1.0f);
            }
            p = fminf(fmaxf(p, EPS_F), 1.0f - EPS_F);
            float u = noise[t];
            u = fminf(fmaxf(u, EPS_F), 1.0f - EPS_F);
            const float z = ((logf(p) - log1pf(-p)) + logf(u)) - log1pf(-u);
            hard[t] = (z > 0.0f) ? (unsigned char)1 : (unsigned char)0;
        }
    }
}

// ---------------------- K4: per-row length, forced boundary, scan -> starts, n_b, mask
__global__ void k_scan(const float* __restrict__ mask, const unsigned char* __restrict__ hard,
                       int* __restrict__ starts, int* __restrict__ nb_arr,
                       int* __restrict__ len_arr, float* __restrict__ out_short) {
    __shared__ int sc[256];
    __shared__ int s_len;
    const int b = blockIdx.x, tid = threadIdx.x;
    const int base = b * L_SEQ;

    // row length = sum(mask) (contiguous prefix of ones)
    int cnt = 0;
    const float4* m4 = (const float4*)(mask + base);
    for (int i = tid; i < L_SEQ / 4; i += 256) {
        const float4 v = m4[i];
        cnt += (v.x != 0.0f) + (v.y != 0.0f) + (v.z != 0.0f) + (v.w != 0.0f);
    }
    sc[tid] = cnt;
    __syncthreads();
    for (int ofs = 128; ofs > 0; ofs >>= 1) {
        if (tid < ofs) sc[tid] += sc[tid + ofs];
        __syncthreads();
    }
    if (tid == 0) s_len = sc[0];
    __syncthreads();
    const int len = s_len;

    // adjusted hard bits for this thread's contiguous chunk [32*tid, 32*tid+32)
    const int i0 = tid * 32;
    unsigned int bits = 0;
    int c = 0;
#pragma unroll
    for (int j = 0; j < 32; ++j) {
        const int i = i0 + j;
        int h = (i < len) ? (int)hard[base + i] : 0;
        if (len < L_SEQ && i == len - 1) h = 1;  // forced boundary at last real token
        bits |= (unsigned int)h << j;
        c += h;
    }
    __syncthreads();
    sc[tid] = c;
    __syncthreads();
    // inclusive Hillis-Steele scan over 256 thread counts
    for (int ofs = 1; ofs < 256; ofs <<= 1) {
        const int v = (tid >= ofs) ? sc[tid - ofs] : 0;
        __syncthreads();
        sc[tid] += v;
        __syncthreads();
    }
    const int off = sc[tid] - c;
    const int nb = sc[255];

    int run = off;
#pragma unroll
    for (int j = 0; j < 32; ++j)
        if ((bits >> j) & 1u) { starts[base + run] = i0 + j; ++run; }

    if (tid == 0) { nb_arr[b] = nb; len_arr[b] = len; }

    for (int i = tid; i < L_SEQ; i += 256) out_short[base + i] = (i < nb) ? 1.0f : 0.0f;
}

// --------------------------------------------- K5: one wave per segment, mean-pool
__global__ __launch_bounds__(256) void k_pool(
    const float* __restrict__ hidden, const int* __restrict__ starts,
    const int* __restrict__ nb_arr, const int* __restrict__ len_arr,
    float* __restrict__ pooled) {
    const int tid  = threadIdx.x;
    const int lane = tid & 63;
    const int wid  = blockIdx.x * 4 + (tid >> 6);
    const int b    = wid >> 13;       // / 8192
    const int s    = wid & (L_SEQ - 1);
    const int nb   = nb_arr[b];

    float4 res = {0.f, 0.f, 0.f, 0.f};
    if (s < nb) {
        const int start = (s == 0) ? 0 : starts[b * L_SEQ + s];
        const int end   = (s + 1 < nb) ? starts[b * L_SEQ + s + 1] : len_arr[b];
        float4 acc = {0.f, 0.f, 0.f, 0.f};
        for (int t = start; t < end; ++t) {
            const float4 v = ((const float4*)hidden)[(b * L_SEQ + t) * 64 + lane];
            acc.x += v.x; acc.y += v.y; acc.z += v.z; acc.w += v.w;
        }
        const float cntf = (float)(end - start);
        res.x = acc.x / cntf; res.y = acc.y / cntf; res.z = acc.z / cntf; res.w = acc.w / cntf;
    }
    ((float4*)pooled)[(size_t)wid * 64 + lane] = res;
}

// ---------------------------------------------------- K6: scalars (loss via lgamma)
__global__ void k_final(const int* __restrict__ nb_arr, const int* __restrict__ len_arr,
                        float* __restrict__ out_scal) {
    if (threadIdx.x == 0) {
        int nb = 0, ln = 0;
        for (int b = 0; b < B_BATCH; ++b) { nb += nb_arr[b]; ln += len_arr[b]; }
        const double k = (double)nb, n = (double)ln;
        const double logp = lgamma(n + 1.0) - lgamma(k + 1.0) - lgamma(n - k + 1.0)
                            + k * log(0.2) + (n - k) * log(0.8);
        const double loss = -logp / n;
        out_scal[0] = (float)loss;
        out_scal[1] = (float)nb;
        out_scal[2] = (float)ln;
    }
}

extern "C" void kernel_launch(void* const* d_in, const int* in_sizes, int n_in,
                              void* d_out, int out_size, void* d_ws, size_t ws_size,
                              hipStream_t stream) {
    const float* hidden = (const float*)d_in[0];
    const float* Wq     = (const float*)d_in[1];
    const float* Wk     = (const float*)d_in[2];
    const float* noise  = (const float*)d_in[3];
    const float* mask   = (const float*)d_in[4];
    float* out = (float*)d_out;
    char* ws = (char*)d_ws;

    float*          M      = (float*)(ws);                 // dead after k_packB
    int*            starts = (int*)(ws);                   // reuses M region (k_scan onward)
    unsigned short* Bpack  = (unsigned short*)(ws + 262144);
    unsigned char*  hard   = (unsigned char*)(ws + 524288);
    int*            nb_arr = (int*)(ws + 589824);
    int*            len_arr= (int*)(ws + 589856);

    float* pooled = out;
    float* scal   = out + (size_t)BL * D_DIM;
    float* shortm = scal + 3;

    k_matM   <<<dim3(16, 16), dim3(16, 16), 0, stream>>>(Wq, Wk, M);
    k_packB  <<<256, 64, 0, stream>>>(M, Bpack);
    k_cosmfma<<<BL / 64, 256, 0, stream>>>(hidden, Bpack, noise, hard);
    k_scan   <<<B_BATCH, 256, 0, stream>>>(mask, hard, starts, nb_arr, len_arr, shortm);
    k_pool   <<<BL / 4, 256, 0, stream>>>(hidden, starts, nb_arr, len_arr, pooled);
    k_final  <<<1, 64, 0, stream>>>(nb_arr, len_arr, scal);
}

// Round 4
// 189.318 us; speedup vs baseline: 1.4115x; 1.0994x over previous
//
#include <hip/hip_runtime.h>
#include <hip/hip_bf16.h>
#include <math.h>

#define L_SEQ 8192
#define B_BATCH 8
#define D_DIM 256
#define BL (B_BATCH * L_SEQ)
#define EPS_F 1.1920929e-07f

typedef __attribute__((ext_vector_type(8))) short short8;
typedef __attribute__((ext_vector_type(4))) float f32x4;
typedef __attribute__((ext_vector_type(4))) unsigned short u16x4;

// ws layout (bytes):
//   [0,       262144)  starts int32 BL (k_scan+)
//   [262144,  524288)  Bpack bf16: 2 segs (M1,M2) x 8 k8 x 16 ct fragments x 64 lanes x 8
//   [524288,  589824)  hard  uint8  BL
//   [589824,  589856)  n_b   int32  8
//   [589856,  589888)  len   int32  8

__device__ inline unsigned short f2bf(float x) {
    __hip_bfloat16 b = __float2bfloat16(x);
    return *(unsigned short*)&b;
}
__device__ inline float bf2f(unsigned short u) {
    __hip_bfloat16 b = *(__hip_bfloat16*)&u;
    return __bfloat162float(b);
}

// ------------------- K1: fused M = Wq^T*Wk - I  ->  bf16 hi/lo MFMA B-fragment pack
// Grid 128 blocks: block f = (k8, ct) computes the 32x16 tile M[k8*32..+32][ct*16..+16]
// and writes hi frag (k8*16+ct) and lo frag (+128) directly. No M round-trip.
__global__ __launch_bounds__(256) void k_matMpack(
    const float* __restrict__ Wq, const float* __restrict__ Wk,
    unsigned short* __restrict__ Bpack) {
    __shared__ float Aq[64][33];
    __shared__ float Ak[64][17];
    const int f   = blockIdx.x;       // 0..127
    const int k8  = f >> 4, ct = f & 15;
    const int tid = threadIdx.x;
    const int n   = tid & 15;         // col within ct tile
    const int k   = tid >> 4;         // 0..15; thread owns rows k and k+16 of the strip
    float a0 = 0.f, a1 = 0.f;
    for (int e0 = 0; e0 < 256; e0 += 64) {
        for (int i = tid; i < 64 * 32; i += 256) {
            const int e = i >> 5, d = i & 31;
            Aq[e][d] = Wq[(e0 + e) * 256 + k8 * 32 + d];
        }
        for (int i = tid; i < 64 * 16; i += 256) {
            const int e = i >> 4, d = i & 15;
            Ak[e][d] = Wk[(e0 + e) * 256 + ct * 16 + d];
        }
        __syncthreads();
#pragma unroll 8
        for (int e = 0; e < 64; ++e) {
            a0 += Aq[e][k] * Ak[e][n];
            a1 += Aq[e][k + 16] * Ak[e][n];
        }
        __syncthreads();
    }
    const int col = ct * 16 + n;
    const float M0 = a0 - ((k8 * 32 + k)      == col ? 1.0f : 0.0f);
    const float M1 = a1 - ((k8 * 32 + k + 16) == col ? 1.0f : 0.0f);
    const unsigned short h0 = f2bf(M0), h1 = f2bf(M1);
    const unsigned short l0 = f2bf(M0 - bf2f(h0)), l1 = f2bf(M1 - bf2f(h1));
    unsigned short* dstH = Bpack + (size_t)(k8 * 16 + ct) * 512;
    unsigned short* dstL = dstH + 128 * 512;
    const int q0 = k >> 3, j0 = k & 7;
    const int q1 = (k + 16) >> 3;
    dstH[(q0 * 16 + n) * 8 + j0] = h0;
    dstH[(q1 * 16 + n) * 8 + j0] = h1;
    dstL[(q0 * 16 + n) * 8 + j0] = l0;
    dstL[(q1 * 16 + n) * 8 + j0] = l1;
}

// ------------------------------ K2: normalize + MFMA correction GEMM + cos + hard bit
// Block = 256 thr = 4 waves, 64 output tokens [T0, T0+64).
// cos(t) = hn_{t-1}.hn_t (exact fp32, at STAGE time) + hn_{t-1}^T(M-I)hn_t (bf16 hi/lo).
// v4 COLUMN-SPLIT: wave w computes ALL 64 rows x cols [w*64, w*64+64) -> each B frag
// loaded by exactly ONE wave: B traffic 1 MB -> 256 KB per block (4x L2 cut; v3 was
// L2-latency/BW bound on B at 71 us, MfmaUtil 14%).
// B prefetch: 3-buffer rotation, refill->use distance = 2 full strips (~400cy > L2 lat).
// Two block barriers total (post-stage, pre-final); Vpart LDS reduce across waves.
#define RS 264   // LDS row stride in bf16 elems: 528 B
#define MM(A,Bv,C) __builtin_amdgcn_mfma_f32_16x16x32_bf16((A),(Bv),(C),0,0,0)
#define MFMA16(V0,V1,V2,V3,BN) \
    acc[0][0]=MM(V0,BN##_0,acc[0][0]); acc[0][1]=MM(V0,BN##_1,acc[0][1]); \
    acc[0][2]=MM(V0,BN##_2,acc[0][2]); acc[0][3]=MM(V0,BN##_3,acc[0][3]); \
    acc[1][0]=MM(V1,BN##_0,acc[1][0]); acc[1][1]=MM(V1,BN##_1,acc[1][1]); \
    acc[1][2]=MM(V1,BN##_2,acc[1][2]); acc[1][3]=MM(V1,BN##_3,acc[1][3]); \
    acc[2][0]=MM(V2,BN##_0,acc[2][0]); acc[2][1]=MM(V2,BN##_1,acc[2][1]); \
    acc[2][2]=MM(V2,BN##_2,acc[2][2]); acc[2][3]=MM(V2,BN##_3,acc[2][3]); \
    acc[3][0]=MM(V3,BN##_0,acc[3][0]); acc[3][1]=MM(V3,BN##_1,acc[3][1]); \
    acc[3][2]=MM(V3,BN##_2,acc[3][2]); acc[3][3]=MM(V3,BN##_3,acc[3][3]);
#define LOADB(BN,S) \
    BN##_0 = Bld[(((S) * 16) + w4 + 0) * 64]; \
    BN##_1 = Bld[(((S) * 16) + w4 + 1) * 64]; \
    BN##_2 = Bld[(((S) * 16) + w4 + 2) * 64]; \
    BN##_3 = Bld[(((S) * 16) + w4 + 3) * 64];
#define STRIP_HL(S,BN) { \
    const int co = ((S) & 7) * 32; \
    const short8 hv0 = *(const short8*)(hA0 + co), hv1 = *(const short8*)(hA1 + co), \
                 hv2 = *(const short8*)(hA2 + co), hv3 = *(const short8*)(hA3 + co); \
    const short8 lv0 = *(const short8*)(lA0 + co), lv1 = *(const short8*)(lA1 + co), \
                 lv2 = *(const short8*)(lA2 + co), lv3 = *(const short8*)(lA3 + co); \
    MFMA16(hv0,hv1,hv2,hv3,BN); \
    MFMA16(lv0,lv1,lv2,lv3,BN); \
    LOADB(BN,(S)+3); }
#define STRIP_H(S,BN) { \
    const int co = ((S) & 7) * 32; \
    const short8 hv0 = *(const short8*)(hA0 + co), hv1 = *(const short8*)(hA1 + co), \
                 hv2 = *(const short8*)(hA2 + co), hv3 = *(const short8*)(hA3 + co); \
    MFMA16(hv0,hv1,hv2,hv3,BN); \
    if ((S) + 3 < 16) { LOADB(BN,(S)+3); } }

__global__ __launch_bounds__(256, 2) void k_cosmfma(
    const float* __restrict__ hidden, const unsigned short* __restrict__ Bpack,
    const float* __restrict__ noise, unsigned char* __restrict__ hard) {
    __shared__ __attribute__((aligned(16))) unsigned short hiA[65 * RS]; // 34,320 B
    __shared__ __attribute__((aligned(16))) unsigned short loA[65 * RS]; // 34,320 B
    __shared__ float Vpart[4][64];                                       //  1,024 B
    __shared__ float dots[64];                                           //    256 B

    const int tid  = threadIdx.x;
    const int lane = tid & 63;
    const int w    = tid >> 6;        // wave 0..3
    const int w16  = w * 16;
    const int w4   = w * 4;           // this wave's ct base (cols [w*64, w*64+64))
    const int T0   = blockIdx.x * 64;

    const short8* __restrict__ Bld = (const short8*)Bpack + lane;

    // 3-buffer B pipeline; preload strips 0,1,2 (fly during staging)
    short8 bA_0, bA_1, bA_2, bA_3, bB_0, bB_1, bB_2, bB_3, bC_0, bC_1, bC_2, bC_3;
    LOADB(bA, 0);
    LOADB(bB, 1);
    LOADB(bC, 2);

    // ---- stage slab: rows w16..w16+16 (token T0-1+row), hi/lo bf16 + exact pair dots ----
    {
        int tokA = T0 - 1 + w16; if (tokA < 0) tokA = 0;       // row w16
        float4 vb0 = ((const float4*)hidden)[(size_t)tokA * 64 + lane];
        float4 vb1 = ((const float4*)hidden)[(size_t)(T0 + w16) * 64 + lane];  // row w16+1
        float4 hp4 = {0.f, 0.f, 0.f, 0.f};
#pragma unroll 1
        for (int ii = 0; ii <= 16; ++ii) {
            const float4 vcur = vb0;
            vb0 = vb1;
            if (ii + 2 <= 16)   // prefetch row w16+ii+2 = token T0+w16+ii+1
                vb1 = ((const float4*)hidden)[(size_t)(T0 + w16 + ii + 1) * 64 + lane];
            float ss = vcur.x * vcur.x + vcur.y * vcur.y + vcur.z * vcur.z + vcur.w * vcur.w;
#pragma unroll
            for (int sh = 32; sh >= 1; sh >>= 1) ss += __shfl_xor(ss, sh);
            const float inv = 1.0f / fmaxf(sqrtf(ss), 1e-12f);
            float4 h4;
            h4.x = vcur.x * inv; h4.y = vcur.y * inv;
            h4.z = vcur.z * inv; h4.w = vcur.w * inv;
            const unsigned short hx = f2bf(h4.x), hy = f2bf(h4.y),
                                 hz = f2bf(h4.z), hw2 = f2bf(h4.w);
            const u16x4 hv4 = {hx, hy, hz, hw2};
            const u16x4 lv4 = {f2bf(h4.x - bf2f(hx)), f2bf(h4.y - bf2f(hy)),
                               f2bf(h4.z - bf2f(hz)), f2bf(h4.w - bf2f(hw2))};
            const int i = w16 + ii;
            *(u16x4*)&hiA[i * RS + lane * 4] = hv4;
            *(u16x4*)&loA[i * RS + lane * 4] = lv4;
            if (ii > 0) {   // exact fp32 main dot hn_{i-1}.hn_i  -> token T0 + (i-1)
                float pd = h4.x * hp4.x + h4.y * hp4.y + h4.z * hp4.z + h4.w * hp4.w;
#pragma unroll
                for (int sh = 32; sh >= 1; sh >>= 1) pd += __shfl_xor(pd, sh);
                if (lane == 0) dots[i - 1] = pd;
            }
            hp4 = h4;
        }
    }
    __syncthreads();   // waves read other waves' slab rows below

    // A-frag pointers: frag af covers slab rows af*16 + m; lane holds A[m][q*8+j]
    const int m = lane & 15, q = lane >> 4;
    const unsigned short* __restrict__ hA0 = &hiA[(0  + m) * RS + q * 8];
    const unsigned short* __restrict__ hA1 = &hiA[(16 + m) * RS + q * 8];
    const unsigned short* __restrict__ hA2 = &hiA[(32 + m) * RS + q * 8];
    const unsigned short* __restrict__ hA3 = &hiA[(48 + m) * RS + q * 8];
    const unsigned short* __restrict__ lA0 = &loA[(0  + m) * RS + q * 8];
    const unsigned short* __restrict__ lA1 = &loA[(16 + m) * RS + q * 8];
    const unsigned short* __restrict__ lA2 = &loA[(32 + m) * RS + q * 8];
    const unsigned short* __restrict__ lA3 = &loA[(48 + m) * RS + q * 8];

    f32x4 acc[4][4];
#pragma unroll
    for (int af = 0; af < 4; ++af)
#pragma unroll
        for (int c = 0; c < 4; ++c) { f32x4 z = {0.f, 0.f, 0.f, 0.f}; acc[af][c] = z; }

    // strips 0..7: seg0 (h & l A-frags); strips 8..15: seg1 (h only)
    STRIP_HL(0, bA)  STRIP_HL(1, bB)  STRIP_HL(2, bC)  STRIP_HL(3, bA)
    STRIP_HL(4, bB)  STRIP_HL(5, bC)  STRIP_HL(6, bA)  STRIP_HL(7, bB)
    STRIP_H (8, bC)  STRIP_H (9, bA)  STRIP_H (10, bB) STRIP_H (11, bC)
    STRIP_H (12, bA) STRIP_H (13, bB) STRIP_H (14, bC) STRIP_H (15, bA)

    // ---- epilogue: per-row partial over this wave's 64 cols, then cross-wave reduce ----
    // D row = af*16 + q*4 + r (slab row of V; token T0+row), D col = (w4+c)*16 + m.
#pragma unroll
    for (int af = 0; af < 4; ++af) {
#pragma unroll
        for (int r = 0; r < 4; ++r) {
            const int row = af * 16 + (q << 2) + r;
            const int ib  = (row + 1) * RS + w4 * 16 + m;
            float pp = acc[af][0][r] * (bf2f(hiA[ib     ]) + bf2f(loA[ib     ]))
                     + acc[af][1][r] * (bf2f(hiA[ib + 16]) + bf2f(loA[ib + 16]))
                     + acc[af][2][r] * (bf2f(hiA[ib + 32]) + bf2f(loA[ib + 32]))
                     + acc[af][3][r] * (bf2f(hiA[ib + 48]) + bf2f(loA[ib + 48]));
            pp += __shfl_xor(pp, 1);
            pp += __shfl_xor(pp, 2);
            pp += __shfl_xor(pp, 4);
            pp += __shfl_xor(pp, 8);
            if (m == 0) Vpart[w][row] = pp;
        }
    }
    __syncthreads();
    if (lane < 16) {
        const int rl = w16 + lane;      // token t = T0 + rl
        const float part = Vpart[0][rl] + Vpart[1][rl] + Vpart[2][rl] + Vpart[3][rl];
        const int t = T0 + rl;
        const int l = t & (L_SEQ - 1);
        float p;
        if (l == 0) {
            p = 1.0f;
        } else {
            p = (1.0f - (part + dots[rl])) * 0.5f;
            p = fminf(fmaxf(p, 0.0f), 1.0f);
        }
        p = fminf(fmaxf(p, EPS_F), 1.0f - EPS_F);
        float u = noise[t];
        u = fminf(fmaxf(u, EPS_F), 1.0f - EPS_F);
        const float z = ((logf(p) - log1pf(-p)) + logf(u)) - log1pf(-u);
        hard[t] = (z > 0.0f) ? (unsigned char)1 : (unsigned char)0;
    }
}

// ---------------------- K3: per-row length, forced boundary, scan -> starts, n_b, mask
// 1024 threads/row; vectorized loads; shfl-based hierarchical scan (3 barriers total).
__global__ __launch_bounds__(1024) void k_scan(
    const float* __restrict__ mask, const unsigned char* __restrict__ hard,
    int* __restrict__ starts, int* __restrict__ nb_arr,
    int* __restrict__ len_arr, float* __restrict__ out_short) {
    __shared__ int wsum[16];
    __shared__ int s_len;
    const int b = blockIdx.x, tid = threadIdx.x;
    const int lane = tid & 63, wv = tid >> 6;   // 16 waves
    const int base = b * L_SEQ;

    // row length = sum(mask): 8 floats per thread
    const float4* m4 = (const float4*)(mask + base);
    const float4 va = m4[tid * 2], vb = m4[tid * 2 + 1];
    int cnt = (va.x != 0.f) + (va.y != 0.f) + (va.z != 0.f) + (va.w != 0.f)
            + (vb.x != 0.f) + (vb.y != 0.f) + (vb.z != 0.f) + (vb.w != 0.f);
#pragma unroll
    for (int sh = 32; sh >= 1; sh >>= 1) cnt += __shfl_xor(cnt, sh);
    if (lane == 0) wsum[wv] = cnt;
    __syncthreads();
    if (tid == 0) {
        int s = 0;
        for (int i = 0; i < 16; ++i) s += wsum[i];
        s_len = s;
    }
    __syncthreads();
    const int len = s_len;

    // adjusted hard bits for this thread's 8 tokens [8*tid, 8*tid+8)
    const int i0 = tid * 8;
    const uint2 hb = ((const uint2*)(hard + base))[tid];
    int c = 0;
    unsigned int bits = 0;
#pragma unroll
    for (int j = 0; j < 8; ++j) {
        const unsigned int byte = ((j < 4 ? hb.x : hb.y) >> (8 * (j & 3))) & 0xffu;
        int h = ((i0 + j) < len) ? (int)(byte != 0u) : 0;
        if (len < L_SEQ && (i0 + j) == len - 1) h = 1;  // forced boundary at last real token
        bits |= (unsigned int)h << j;
        c += h;
    }
    // inclusive wave scan of counts
    int x = c;
#pragma unroll
    for (int ofs = 1; ofs < 64; ofs <<= 1) {
        const int t = __shfl_up(x, ofs);
        if (lane >= ofs) x += t;
    }
    if (lane == 63) wsum[wv] = x;
    __syncthreads();
    int woff = 0, nb = 0;
#pragma unroll
    for (int i = 0; i < 16; ++i) {
        const int t = wsum[i];
        nb += t;
        if (i < wv) woff += t;
    }
    int run = woff + x - c;   // exclusive prefix for this thread
#pragma unroll
    for (int j = 0; j < 8; ++j)
        if ((bits >> j) & 1u) { starts[base + run] = i0 + j; ++run; }

    if (tid == 0) { nb_arr[b] = nb; len_arr[b] = len; }

    float4 o0, o1;
    o0.x = (i0 + 0) < nb ? 1.f : 0.f; o0.y = (i0 + 1) < nb ? 1.f : 0.f;
    o0.z = (i0 + 2) < nb ? 1.f : 0.f; o0.w = (i0 + 3) < nb ? 1.f : 0.f;
    o1.x = (i0 + 4) < nb ? 1.f : 0.f; o1.y = (i0 + 5) < nb ? 1.f : 0.f;
    o1.z = (i0 + 6) < nb ? 1.f : 0.f; o1.w = (i0 + 7) < nb ? 1.f : 0.f;
    float4* os4 = (float4*)(out_short + base);
    os4[tid * 2] = o0;
    os4[tid * 2 + 1] = o1;
}

// --------------------------------------------- K4: one wave per segment, mean-pool
__global__ __launch_bounds__(256) void k_pool(
    const float* __restrict__ hidden, const int* __restrict__ starts,
    const int* __restrict__ nb_arr, const int* __restrict__ len_arr,
    float* __restrict__ pooled) {
    const int tid  = threadIdx.x;
    const int lane = tid & 63;
    const int wid  = blockIdx.x * 4 + (tid >> 6);
    const int b    = wid >> 13;       // / 8192
    const int s    = wid & (L_SEQ - 1);
    const int nb   = nb_arr[b];

    float4 res = {0.f, 0.f, 0.f, 0.f};
    if (s < nb) {
        const int start = (s == 0) ? 0 : starts[b * L_SEQ + s];
        const int end   = (s + 1 < nb) ? starts[b * L_SEQ + s + 1] : len_arr[b];
        float4 acc = {0.f, 0.f, 0.f, 0.f};
        for (int t = start; t < end; ++t) {
            const float4 v = ((const float4*)hidden)[(b * L_SEQ + t) * 64 + lane];
            acc.x += v.x; acc.y += v.y; acc.z += v.z; acc.w += v.w;
        }
        const float cntf = (float)(end - start);
        res.x = acc.x / cntf; res.y = acc.y / cntf; res.z = acc.z / cntf; res.w = acc.w / cntf;
    }
    ((float4*)pooled)[(size_t)wid * 64 + lane] = res;
}

// ---------------------------------------------------- K5: scalars (loss via lgamma)
__global__ void k_final(const int* __restrict__ nb_arr, const int* __restrict__ len_arr,
                        float* __restrict__ out_scal) {
    if (threadIdx.x == 0) {
        int nb = 0, ln = 0;
        for (int b = 0; b < B_BATCH; ++b) { nb += nb_arr[b]; ln += len_arr[b]; }
        const double k = (double)nb, n = (double)ln;
        const double logp = lgamma(n + 1.0) - lgamma(k + 1.0) - lgamma(n - k + 1.0)
                            + k * log(0.2) + (n - k) * log(0.8);
        const double loss = -logp / n;
        out_scal[0] = (float)loss;
        out_scal[1] = (float)nb;
        out_scal[2] = (float)ln;
    }
}

extern "C" void kernel_launch(void* const* d_in, const int* in_sizes, int n_in,
                              void* d_out, int out_size, void* d_ws, size_t ws_size,
                              hipStream_t stream) {
    const float* hidden = (const float*)d_in[0];
    const float* Wq     = (const float*)d_in[1];
    const float* Wk     = (const float*)d_in[2];
    const float* noise  = (const float*)d_in[3];
    const float* mask   = (const float*)d_in[4];
    float* out = (float*)d_out;
    char* ws = (char*)d_ws;

    int*            starts = (int*)(ws);
    unsigned short* Bpack  = (unsigned short*)(ws + 262144);
    unsigned char*  hard   = (unsigned char*)(ws + 524288);
    int*            nb_arr = (int*)(ws + 589824);
    int*            len_arr= (int*)(ws + 589856);

    float* pooled = out;
    float* scal   = out + (size_t)BL * D_DIM;
    float* shortm = scal + 3;

    k_matMpack<<<128, 256, 0, stream>>>(Wq, Wk, Bpack);
    k_cosmfma <<<BL / 64, 256, 0, stream>>>(hidden, Bpack, noise, hard);
    k_scan    <<<B_BATCH, 1024, 0, stream>>>(mask, hard, starts, nb_arr, len_arr, shortm);
    k_pool    <<<BL / 4, 256, 0, stream>>>(hidden, starts, nb_arr, len_arr, pooled);
    k_final   <<<1, 64, 0, stream>>>(nb_arr, len_arr, scal);
}

// Round 5
// 180.593 us; speedup vs baseline: 1.4797x; 1.0483x over previous
//
#include <hip/hip_runtime.h>
#include <hip/hip_bf16.h>
#include <math.h>

#define L_SEQ 8192
#define B_BATCH 8
#define D_DIM 256
#define BL (B_BATCH * L_SEQ)
#define EPS_F 1.1920929e-07f

typedef __attribute__((ext_vector_type(8))) short short8;
typedef __attribute__((ext_vector_type(4))) float f32x4;
typedef __attribute__((ext_vector_type(4))) unsigned short u16x4;

// ws layout (bytes):
//   [0,       262144)  starts int32 BL (k_scan+)
//   [262144,  524288)  Bpack bf16: 2 segs (M1,M2) x 8 k8 x 16 ct fragments x 64 lanes x 8
//   [524288,  589824)  hard  uint8  BL
//   [589824,  589856)  n_b   int32  8
//   [589856,  589888)  len   int32  8

__device__ inline unsigned short f2bf(float x) {
    __hip_bfloat16 b = __float2bfloat16(x);
    return *(unsigned short*)&b;
}
__device__ inline float bf2f(unsigned short u) {
    __hip_bfloat16 b = *(__hip_bfloat16*)&u;
    return __bfloat162float(b);
}

// ------------------- K1: fused M = Wq^T*Wk - I  ->  bf16 hi/lo MFMA B-fragment pack
// Grid 128 blocks: block f = (k8, ct) computes the 32x16 tile M[k8*32..+32][ct*16..+16]
// and writes hi frag (k8*16+ct) and lo frag (+128) directly. No M round-trip.
__global__ __launch_bounds__(256) void k_matMpack(
    const float* __restrict__ Wq, const float* __restrict__ Wk,
    unsigned short* __restrict__ Bpack) {
    __shared__ float Aq[64][33];
    __shared__ float Ak[64][17];
    const int f   = blockIdx.x;       // 0..127
    const int k8  = f >> 4, ct = f & 15;
    const int tid = threadIdx.x;
    const int n   = tid & 15;         // col within ct tile
    const int k   = tid >> 4;         // 0..15; thread owns rows k and k+16 of the strip
    float a0 = 0.f, a1 = 0.f;
    for (int e0 = 0; e0 < 256; e0 += 64) {
        for (int i = tid; i < 64 * 32; i += 256) {
            const int e = i >> 5, d = i & 31;
            Aq[e][d] = Wq[(e0 + e) * 256 + k8 * 32 + d];
        }
        for (int i = tid; i < 64 * 16; i += 256) {
            const int e = i >> 4, d = i & 15;
            Ak[e][d] = Wk[(e0 + e) * 256 + ct * 16 + d];
        }
        __syncthreads();
#pragma unroll 8
        for (int e = 0; e < 64; ++e) {
            a0 += Aq[e][k] * Ak[e][n];
            a1 += Aq[e][k + 16] * Ak[e][n];
        }
        __syncthreads();
    }
    const int col = ct * 16 + n;
    const float M0 = a0 - ((k8 * 32 + k)      == col ? 1.0f : 0.0f);
    const float M1 = a1 - ((k8 * 32 + k + 16) == col ? 1.0f : 0.0f);
    const unsigned short h0 = f2bf(M0), h1 = f2bf(M1);
    const unsigned short l0 = f2bf(M0 - bf2f(h0)), l1 = f2bf(M1 - bf2f(h1));
    unsigned short* dstH = Bpack + (size_t)(k8 * 16 + ct) * 512;
    unsigned short* dstL = dstH + 128 * 512;
    const int q0 = k >> 3, j0 = k & 7;
    const int q1 = (k + 16) >> 3;
    dstH[(q0 * 16 + n) * 8 + j0] = h0;
    dstH[(q1 * 16 + n) * 8 + j0] = h1;
    dstL[(q0 * 16 + n) * 8 + j0] = l0;
    dstL[(q1 * 16 + n) * 8 + j0] = l1;
}

// ------------------------------ K2: normalize + MFMA correction GEMM + cos + hard bit
// v5: 512 thr = 8 waves/block, output split 2x4: wave (wr,wc) owns rows [wr*32,+32) x
// cols [wc*64,+64). LDS unchanged (~70 KB, 2 blocks/CU) -> 16 waves/CU = 4 waves/SIMD
// (2x v4's occupancy; v4 was latency-stalled at 2 waves/SIMD, MfmaUtil 17%).
// Aggregate LDS A-frag traffic unchanged (row-split halves per-wave reads); B L2
// traffic 2x (rows halves share B) = 512 MB @ ~9 TB/s, far under the 34 TB/s ceiling.
// Each wave stages 9 slab rows (overlap row duplicated, benign). 2 barriers total.
#define RS 264   // LDS row stride in bf16 elems: 528 B
#define MM(A,Bv,C) __builtin_amdgcn_mfma_f32_16x16x32_bf16((A),(Bv),(C),0,0,0)
#define MFMA8(V0,V1,BN) \
    acc[0][0]=MM(V0,BN##_0,acc[0][0]); acc[0][1]=MM(V0,BN##_1,acc[0][1]); \
    acc[0][2]=MM(V0,BN##_2,acc[0][2]); acc[0][3]=MM(V0,BN##_3,acc[0][3]); \
    acc[1][0]=MM(V1,BN##_0,acc[1][0]); acc[1][1]=MM(V1,BN##_1,acc[1][1]); \
    acc[1][2]=MM(V1,BN##_2,acc[1][2]); acc[1][3]=MM(V1,BN##_3,acc[1][3]);
#define LOADB(BN,S) \
    BN##_0 = Bld[(((S) * 16) + wc4 + 0) * 64]; \
    BN##_1 = Bld[(((S) * 16) + wc4 + 1) * 64]; \
    BN##_2 = Bld[(((S) * 16) + wc4 + 2) * 64]; \
    BN##_3 = Bld[(((S) * 16) + wc4 + 3) * 64];
#define STRIP_HL(S,BN) { \
    const int co = ((S) & 7) * 32; \
    const short8 hv0 = *(const short8*)(hA0 + co), hv1 = *(const short8*)(hA1 + co); \
    const short8 lv0 = *(const short8*)(lA0 + co), lv1 = *(const short8*)(lA1 + co); \
    MFMA8(hv0, hv1, BN); \
    MFMA8(lv0, lv1, BN); \
    LOADB(BN, (S) + 3); }
#define STRIP_H(S,BN) { \
    const int co = ((S) & 7) * 32; \
    const short8 hv0 = *(const short8*)(hA0 + co), hv1 = *(const short8*)(hA1 + co); \
    MFMA8(hv0, hv1, BN); \
    if ((S) + 3 < 16) { LOADB(BN, (S) + 3); } }

__global__ __launch_bounds__(512, 4) void k_cosmfma(
    const float* __restrict__ hidden, const unsigned short* __restrict__ Bpack,
    const float* __restrict__ noise, unsigned char* __restrict__ hard) {
    __shared__ __attribute__((aligned(16))) unsigned short hiA[65 * RS]; // 34,320 B
    __shared__ __attribute__((aligned(16))) unsigned short loA[65 * RS]; // 34,320 B
    __shared__ float Vpart[4][64];                                       //  1,024 B
    __shared__ float dots[64];                                           //    256 B

    const int tid  = threadIdx.x;
    const int lane = tid & 63;
    const int w    = tid >> 6;        // wave 0..7
    const int wr   = w >> 2;          // row half: rows [wr*32, wr*32+32)
    const int wc   = w & 3;           // col quarter: cols [wc*64, wc*64+64)
    const int wr32 = wr * 32;
    const int wc4  = wc * 4;          // ct base
    const int T0   = blockIdx.x * 64;

    const short8* __restrict__ Bld = (const short8*)Bpack + lane;

    // 3-buffer B pipeline; preload strips 0,1,2 (fly during staging)
    short8 bA_0, bA_1, bA_2, bA_3, bB_0, bB_1, bB_2, bB_3, bC_0, bC_1, bC_2, bC_3;
    LOADB(bA, 0);
    LOADB(bB, 1);
    LOADB(bC, 2);

    // ---- stage 9 slab rows [w*8, w*8+8] (token T0-1+row), hi/lo bf16 + pair dots ----
    {
        const int r0 = w * 8;
        int tokA = T0 - 1 + r0; if (tokA < 0) tokA = 0;
        float4 vb0 = ((const float4*)hidden)[(size_t)tokA * 64 + lane];          // row r0
        float4 vb1 = ((const float4*)hidden)[(size_t)(T0 + r0) * 64 + lane];     // row r0+1
        float4 hp4 = {0.f, 0.f, 0.f, 0.f};
#pragma unroll 1
        for (int ii = 0; ii <= 8; ++ii) {
            const float4 vcur = vb0;
            vb0 = vb1;
            if (ii + 2 <= 8)   // prefetch row r0+ii+2 = token T0 + r0 + ii + 1
                vb1 = ((const float4*)hidden)[(size_t)(T0 + r0 + ii + 1) * 64 + lane];
            float ss = vcur.x * vcur.x + vcur.y * vcur.y + vcur.z * vcur.z + vcur.w * vcur.w;
#pragma unroll
            for (int sh = 32; sh >= 1; sh >>= 1) ss += __shfl_xor(ss, sh);
            const float inv = 1.0f / fmaxf(sqrtf(ss), 1e-12f);
            float4 h4;
            h4.x = vcur.x * inv; h4.y = vcur.y * inv;
            h4.z = vcur.z * inv; h4.w = vcur.w * inv;
            const unsigned short hx = f2bf(h4.x), hy = f2bf(h4.y),
                                 hz = f2bf(h4.z), hw2 = f2bf(h4.w);
            const u16x4 hv4 = {hx, hy, hz, hw2};
            const u16x4 lv4 = {f2bf(h4.x - bf2f(hx)), f2bf(h4.y - bf2f(hy)),
                               f2bf(h4.z - bf2f(hz)), f2bf(h4.w - bf2f(hw2))};
            const int i = r0 + ii;
            *(u16x4*)&hiA[i * RS + lane * 4] = hv4;
            *(u16x4*)&loA[i * RS + lane * 4] = lv4;
            if (ii > 0) {   // exact fp32 main dot hn_{i-1}.hn_i  -> token T0 + (i-1)
                float pd = h4.x * hp4.x + h4.y * hp4.y + h4.z * hp4.z + h4.w * hp4.w;
#pragma unroll
                for (int sh = 32; sh >= 1; sh >>= 1) pd += __shfl_xor(pd, sh);
                if (lane == 0) dots[i - 1] = pd;
            }
            hp4 = h4;
        }
    }
    __syncthreads();   // waves read other waves' slab rows below

    // A-frag pointers: frag af covers slab rows wr32 + af*16 + m; lane holds A[m][q*8+j]
    const int m = lane & 15, q = lane >> 4;
    const unsigned short* __restrict__ hA0 = &hiA[(wr32 +  0 + m) * RS + q * 8];
    const unsigned short* __restrict__ hA1 = &hiA[(wr32 + 16 + m) * RS + q * 8];
    const unsigned short* __restrict__ lA0 = &loA[(wr32 +  0 + m) * RS + q * 8];
    const unsigned short* __restrict__ lA1 = &loA[(wr32 + 16 + m) * RS + q * 8];

    f32x4 acc[2][4];
#pragma unroll
    for (int af = 0; af < 2; ++af)
#pragma unroll
        for (int c = 0; c < 4; ++c) { f32x4 z = {0.f, 0.f, 0.f, 0.f}; acc[af][c] = z; }

    // strips 0..7: seg0 (hi B; h & l A-frags); strips 8..15: seg1 (lo B; h only)
    STRIP_HL(0, bA)  STRIP_HL(1, bB)  STRIP_HL(2, bC)  STRIP_HL(3, bA)
    STRIP_HL(4, bB)  STRIP_HL(5, bC)  STRIP_HL(6, bA)  STRIP_HL(7, bB)
    STRIP_H (8, bC)  STRIP_H (9, bA)  STRIP_H (10, bB) STRIP_H (11, bC)
    STRIP_H (12, bA) STRIP_H (13, bB) STRIP_H (14, bC) STRIP_H (15, bA)

    // ---- epilogue: per-row partial over this wave's 64 cols, then cross-wave reduce ----
    // D row = wr32 + af*16 + q*4 + r (token T0+row), D col = (wc4+c)*16 + m.
#pragma unroll
    for (int af = 0; af < 2; ++af) {
#pragma unroll
        for (int r = 0; r < 4; ++r) {
            const int row = wr32 + af * 16 + (q << 2) + r;
            const int ib  = (row + 1) * RS + wc4 * 16 + m;
            float pp = acc[af][0][r] * (bf2f(hiA[ib     ]) + bf2f(loA[ib     ]))
                     + acc[af][1][r] * (bf2f(hiA[ib + 16]) + bf2f(loA[ib + 16]))
                     + acc[af][2][r] * (bf2f(hiA[ib + 32]) + bf2f(loA[ib + 32]))
                     + acc[af][3][r] * (bf2f(hiA[ib + 48]) + bf2f(loA[ib + 48]));
            pp += __shfl_xor(pp, 1);
            pp += __shfl_xor(pp, 2);
            pp += __shfl_xor(pp, 4);
            pp += __shfl_xor(pp, 8);
            if (m == 0) Vpart[wc][row] = pp;
        }
    }
    __syncthreads();
    if (tid < 64) {
        const int rl = tid;             // token t = T0 + rl
        const float part = Vpart[0][rl] + Vpart[1][rl] + Vpart[2][rl] + Vpart[3][rl];
        const int t = T0 + rl;
        const int l = t & (L_SEQ - 1);
        float p;
        if (l == 0) {
            p = 1.0f;
        } else {
            p = (1.0f - (part + dots[rl])) * 0.5f;
            p = fminf(fmaxf(p, 0.0f), 1.0f);
        }
        p = fminf(fmaxf(p, EPS_F), 1.0f - EPS_F);
        float u = noise[t];
        u = fminf(fmaxf(u, EPS_F), 1.0f - EPS_F);
        const float z = ((logf(p) - log1pf(-p)) + logf(u)) - log1pf(-u);
        hard[t] = (z > 0.0f) ? (unsigned char)1 : (unsigned char)0;
    }
}

// ---------------------- K3: per-row length, forced boundary, scan -> starts, n_b, mask
// 1024 threads/row; vectorized loads; shfl-based hierarchical scan (3 barriers total).
__global__ __launch_bounds__(1024) void k_scan(
    const float* __restrict__ mask, const unsigned char* __restrict__ hard,
    int* __restrict__ starts, int* __restrict__ nb_arr,
    int* __restrict__ len_arr, float* __restrict__ out_short) {
    __shared__ int wsum[16];
    __shared__ int s_len;
    const int b = blockIdx.x, tid = threadIdx.x;
    const int lane = tid & 63, wv = tid >> 6;   // 16 waves
    const int base = b * L_SEQ;

    // row length = sum(mask): 8 floats per thread
    const float4* m4 = (const float4*)(mask + base);
    const float4 va = m4[tid * 2], vb = m4[tid * 2 + 1];
    int cnt = (va.x != 0.f) + (va.y != 0.f) + (va.z != 0.f) + (va.w != 0.f)
            + (vb.x != 0.f) + (vb.y != 0.f) + (vb.z != 0.f) + (vb.w != 0.f);
#pragma unroll
    for (int sh = 32; sh >= 1; sh >>= 1) cnt += __shfl_xor(cnt, sh);
    if (lane == 0) wsum[wv] = cnt;
    __syncthreads();
    if (tid == 0) {
        int s = 0;
        for (int i = 0; i < 16; ++i) s += wsum[i];
        s_len = s;
    }
    __syncthreads();
    const int len = s_len;

    // adjusted hard bits for this thread's 8 tokens [8*tid, 8*tid+8)
    const int i0 = tid * 8;
    const uint2 hb = ((const uint2*)(hard + base))[tid];
    int c = 0;
    unsigned int bits = 0;
#pragma unroll
    for (int j = 0; j < 8; ++j) {
        const unsigned int byte = ((j < 4 ? hb.x : hb.y) >> (8 * (j & 3))) & 0xffu;
        int h = ((i0 + j) < len) ? (int)(byte != 0u) : 0;
        if (len < L_SEQ && (i0 + j) == len - 1) h = 1;  // forced boundary at last real token
        bits |= (unsigned int)h << j;
        c += h;
    }
    // inclusive wave scan of counts
    int x = c;
#pragma unroll
    for (int ofs = 1; ofs < 64; ofs <<= 1) {
        const int t = __shfl_up(x, ofs);
        if (lane >= ofs) x += t;
    }
    if (lane == 63) wsum[wv] = x;
    __syncthreads();
    int woff = 0, nb = 0;
#pragma unroll
    for (int i = 0; i < 16; ++i) {
        const int t = wsum[i];
        nb += t;
        if (i < wv) woff += t;
    }
    int run = woff + x - c;   // exclusive prefix for this thread
#pragma unroll
    for (int j = 0; j < 8; ++j)
        if ((bits >> j) & 1u) { starts[base + run] = i0 + j; ++run; }

    if (tid == 0) { nb_arr[b] = nb; len_arr[b] = len; }

    float4 o0, o1;
    o0.x = (i0 + 0) < nb ? 1.f : 0.f; o0.y = (i0 + 1) < nb ? 1.f : 0.f;
    o0.z = (i0 + 2) < nb ? 1.f : 0.f; o0.w = (i0 + 3) < nb ? 1.f : 0.f;
    o1.x = (i0 + 4) < nb ? 1.f : 0.f; o1.y = (i0 + 5) < nb ? 1.f : 0.f;
    o1.z = (i0 + 6) < nb ? 1.f : 0.f; o1.w = (i0 + 7) < nb ? 1.f : 0.f;
    float4* os4 = (float4*)(out_short + base);
    os4[tid * 2] = o0;
    os4[tid * 2 + 1] = o1;
}

// --------------------------------------------- K4: one wave per segment, mean-pool
__global__ __launch_bounds__(256) void k_pool(
    const float* __restrict__ hidden, const int* __restrict__ starts,
    const int* __restrict__ nb_arr, const int* __restrict__ len_arr,
    float* __restrict__ pooled) {
    const int tid  = threadIdx.x;
    const int lane = tid & 63;
    const int wid  = blockIdx.x * 4 + (tid >> 6);
    const int b    = wid >> 13;       // / 8192
    const int s    = wid & (L_SEQ - 1);
    const int nb   = nb_arr[b];

    float4 res = {0.f, 0.f, 0.f, 0.f};
    if (s < nb) {
        const int start = (s == 0) ? 0 : starts[b * L_SEQ + s];
        const int end   = (s + 1 < nb) ? starts[b * L_SEQ + s + 1] : len_arr[b];
        float4 acc = {0.f, 0.f, 0.f, 0.f};
        for (int t = start; t < end; ++t) {
            const float4 v = ((const float4*)hidden)[(b * L_SEQ + t) * 64 + lane];
            acc.x += v.x; acc.y += v.y; acc.z += v.z; acc.w += v.w;
        }
        const float cntf = (float)(end - start);
        res.x = acc.x / cntf; res.y = acc.y / cntf; res.z = acc.z / cntf; res.w = acc.w / cntf;
    }
    ((float4*)pooled)[(size_t)wid * 64 + lane] = res;
}

// ---------------------------------------------------- K5: scalars (loss via lgamma)
__global__ void k_final(const int* __restrict__ nb_arr, const int* __restrict__ len_arr,
                        float* __restrict__ out_scal) {
    if (threadIdx.x == 0) {
        int nb = 0, ln = 0;
        for (int b = 0; b < B_BATCH; ++b) { nb += nb_arr[b]; ln += len_arr[b]; }
        const double k = (double)nb, n = (double)ln;
        const double logp = lgamma(n + 1.0) - lgamma(k + 1.0) - lgamma(n - k + 1.0)
                            + k * log(0.2) + (n - k) * log(0.8);
        const double loss = -logp / n;
        out_scal[0] = (float)loss;
        out_scal[1] = (float)nb;
        out_scal[2] = (float)ln;
    }
}

extern "C" void kernel_launch(void* const* d_in, const int* in_sizes, int n_in,
                              void* d_out, int out_size, void* d_ws, size_t ws_size,
                              hipStream_t stream) {
    const float* hidden = (const float*)d_in[0];
    const float* Wq     = (const float*)d_in[1];
    const float* Wk     = (const float*)d_in[2];
    const float* noise  = (const float*)d_in[3];
    const float* mask   = (const float*)d_in[4];
    float* out = (float*)d_out;
    char* ws = (char*)d_ws;

    int*            starts = (int*)(ws);
    unsigned short* Bpack  = (unsigned short*)(ws + 262144);
    unsigned char*  hard   = (unsigned char*)(ws + 524288);
    int*            nb_arr = (int*)(ws + 589824);
    int*            len_arr= (int*)(ws + 589856);

    float* pooled = out;
    float* scal   = out + (size_t)BL * D_DIM;
    float* shortm = scal + 3;

    k_matMpack<<<128, 256, 0, stream>>>(Wq, Wk, Bpack);
    k_cosmfma <<<BL / 64, 512, 0, stream>>>(hidden, Bpack, noise, hard);
    k_scan    <<<B_BATCH, 1024, 0, stream>>>(mask, hard, starts, nb_arr, len_arr, shortm);
    k_pool    <<<BL / 4, 256, 0, stream>>>(hidden, starts, nb_arr, len_arr, pooled);
    k_final   <<<1, 64, 0, stream>>>(nb_arr, len_arr, scal);
}